// Round 25
// baseline (160.607 us; speedup 1.0000x reference)
//
#include <hip/hip_runtime.h>
#include <math.h>

// LSTMLightweight on MI355X (R25 = R24 with 4x column duplication, 2 waves/SIMD).
//   x[B,T,1] -> linear_in(1->16)+ReLU -> LSTM0(16) -> LSTM1(16) -> fc(16->8)+ReLU -> fc(8->1)
// R24 (122us): 8 real elems/wave, 2 units/lane, 1024 waves = 1/SIMD; per-step
// wall 1144 cyc = 745 issue (448 trans) + ~400 single-wave stall.
// R25: 4 real elems/wave (cols duplicated 4x: col e = element e&3), each lane
// combines ONE unit (q = e>>2): 14 trans/step/lane. Grid 2048 one-wave blocks
// -> 2 waves/SIMD: the co-resident wave's issue fills the stall.
// acc[m][q] extracted with a 2-level select tree (no dynamic indexing);
// h-exchange: shfl_xor(4) pairs units {q, q^1} into a packed word, then
// shfl_xor(8) swaps pair-words -> both B-frag words in every lane.
// Arithmetic identical to R23/R24 (f32 acc, f16 RTN h, one-rcp 7-trans cell):
// absmax must stay 0.001953125.
// Math: K-permuted A so B is lane-local (k=8g+i -> W_ih[.][4g+i] |
// W_hh[.][4g+i-4]; D row=4*(lane>>4)+q', col=lane&15), bias in C-init,
// L1(t) || L0(t+1) in-wave pipeline.

#define L2E 1.4426950408889634f
#define EPB 4         // REAL elements per wave/block (cols duplicated 4x)

typedef _Float16 f16x8 __attribute__((ext_vector_type(8)));
typedef float    f32x4 __attribute__((ext_vector_type(4)));
typedef int      i32x4 __attribute__((ext_vector_type(4)));

__device__ __forceinline__ unsigned pkh(float a, float b) {   // pack 2 f16 RTN
    const _Float16 ha = (_Float16)a, hb = (_Float16)b;
    return (unsigned)__builtin_bit_cast(unsigned short, ha) |
           ((unsigned)__builtin_bit_cast(unsigned short, hb) << 16);
}
__device__ __forceinline__ unsigned h16(float a) {            // f16 bits of a
    return (unsigned)__builtin_bit_cast(unsigned short, (_Float16)a);
}
__device__ __forceinline__ float unpk(unsigned w, int hi) {
    const unsigned short s = (unsigned short)(hi ? (w >> 16) : (w & 0xffffu));
    return (float)__builtin_bit_cast(_Float16, s);
}
__device__ __forceinline__ f16x8 frag4(unsigned w0, unsigned w1,
                                       unsigned w2, unsigned w3) {
    i32x4 t = {(int)w0, (int)w1, (int)w2, (int)w3};
    return __builtin_bit_cast(f16x8, t);
}

// one layer's gates, single product: acc[m] = bias[m] + A·B
#define GATES1(ACC, A, BIAS, BH)                                                      \
    _Pragma("unroll")                                                                 \
    for (int m = 0; m < 4; ++m) {                                                     \
        ACC[m] = BIAS[m];                                                             \
        ACC[m] = __builtin_amdgcn_mfma_f32_16x16x32_f16(A[m], BH, ACC[m], 0, 0, 0);   \
    }

// extract element q of a f32x4 via 2-level select (q0 = q&1, q1 = q&2)
#define SEL4(V) (q1 ? (q0 ? (V)[3] : (V)[2]) : (q0 ? (V)[1] : (V)[0]))

// single-unit one-rcp cell update (7 trans): updates CC, sets HB = f16 bits of h
#define COMBINE1(ACC, CC, HB)                                                         \
    do {                                                                              \
        const float aI_ = SEL4(ACC[0]);                                               \
        const float aF_ = SEL4(ACC[1]);                                               \
        const float aG_ = SEL4(ACC[2]);                                               \
        const float aO_ = SEL4(ACC[3]);                                               \
        const float Ei_ = __builtin_amdgcn_exp2f(-L2E * aI_);                         \
        const float Ef_ = __builtin_amdgcn_exp2f(-L2E * aF_);                         \
        const float Eg_ = __builtin_amdgcn_exp2f(fmaxf(aG_, -40.0f) * (-2.0f * L2E)); \
        const float Eo_ = __builtin_amdgcn_exp2f(-L2E * aO_);                         \
        const float fp_ = 1.0f + Ef_;                                                 \
        const float P_  = (1.0f + Ei_) * (1.0f + Eg_);                                \
        const float N_  = fmaf(CC, P_, (1.0f - Eg_) * fp_);                           \
        CC = N_ * __builtin_amdgcn_rcpf(fp_ * P_);                                    \
        const float Ec_ = __builtin_amdgcn_exp2f(fmaxf(CC, -40.0f) * (-2.0f * L2E));  \
        HB = h16((1.0f - Ec_) *                                                       \
                 __builtin_amdgcn_rcpf((1.0f + Eo_) * (1.0f + Ec_)));                 \
    } while (0)

// rebuild both packed h-words from per-lane h bits (unit q of element e&3):
//   shfl_xor(4): pair {q, q^1} -> word; shfl_xor(8): swap pair-words.
#define EXCH4(HB, W0, W1)                                                             \
    do {                                                                              \
        const unsigned po_ = (unsigned)__shfl_xor((int)(HB), 4, 64);                  \
        const unsigned pw_ = q0 ? (po_ | ((HB) << 16)) : ((HB) | (po_ << 16));        \
        const unsigned ow_ = (unsigned)__shfl_xor((int)pw_, 8, 64);                   \
        W0 = q1 ? ow_ : pw_;                                                          \
        W1 = q1 ? pw_ : ow_;                                                          \
    } while (0)

__global__ __launch_bounds__(64) void lstm_dup4(
    const float* __restrict__ x,
    const float* __restrict__ w_in, const float* __restrict__ b_in,
    const float* __restrict__ w_ih0, const float* __restrict__ w_hh0,
    const float* __restrict__ b_ih0, const float* __restrict__ b_hh0,
    const float* __restrict__ w_ih1, const float* __restrict__ w_hh1,
    const float* __restrict__ b_ih1, const float* __restrict__ b_hh1,
    const float* __restrict__ fc_h_w, const float* __restrict__ fc_h_b,
    const float* __restrict__ fc_o_w, const float* __restrict__ fc_o_b,
    float* __restrict__ out, int B, int T)
{
    const int lane = threadIdx.x;        // 0..63
    const int e    = lane & 15;          // B column; real element = e&3
    const int g    = lane >> 4;          // k-group / D-row group
    const bool q0  = (e & 4) != 0;       // unit-select low bit
    const bool q1  = (e & 8) != 0;       // unit-select high bit
    const int base = blockIdx.x * EPB;
    int rowe = base + (e & 3); if (rowe >= B) rowe = B - 1;

    __shared__ float htab[EPB][16];      // head exchange only

    // ---- A-fragments (f16 RTN), K-permuted (A rows all real; only B dup'd) ----
    f16x8 a0[4], a1[4];
    f32x4 bias0[4], bias1[4];
    #pragma unroll
    for (int m = 0; m < 4; ++m) {
        const int r = 16 * m + e;
        #pragma unroll
        for (int i = 0; i < 8; ++i) {
            const float w0 = (i < 4) ? w_ih0[r * 16 + 4 * g + i]
                                     : w_hh0[r * 16 + 4 * g + (i - 4)];
            const float w1 = (i < 4) ? w_ih1[r * 16 + 4 * g + i]
                                     : w_hh1[r * 16 + 4 * g + (i - 4)];
            a0[m][i] = (_Float16)w0;
            a1[m][i] = (_Float16)w1;
        }
        const int rd = 16 * m + 4 * g;
        #pragma unroll
        for (int q = 0; q < 4; ++q) {
            bias0[m][q] = b_ih0[rd + q] + b_hh0[rd + q];
            bias1[m][q] = b_ih1[rd + q] + b_hh1[rd + q];
        }
    }
    float winq[4], binq[4];
    #pragma unroll
    for (int q = 0; q < 4; ++q) { winq[q] = w_in[4 * g + q]; binq[q] = b_in[4 * g + q]; }

    // ---- state: ONE cell per layer per lane; h as packed f16 words ----
    float c0 = 0.f, c1 = 0.f;
    unsigned h0w0, h0w1;                 // h0(t):  units {4g,4g+1}, {4g+2,4g+3}
    unsigned h1w0 = 0u, h1w1 = 0u;       // h1(t-1)

    const float* xrow = x + (size_t)rowe * T;

    // ---- prologue: L0 at t=0 (h0_{-1}=0) ----
    {
        const float xv = xrow[0];
        const unsigned xw0 = pkh(fmaxf(fmaf(xv, winq[0], binq[0]), 0.0f),
                                 fmaxf(fmaf(xv, winq[1], binq[1]), 0.0f));
        const unsigned xw1 = pkh(fmaxf(fmaf(xv, winq[2], binq[2]), 0.0f),
                                 fmaxf(fmaf(xv, winq[3], binq[3]), 0.0f));
        const f16x8 Bh = frag4(xw0, xw1, 0u, 0u);
        f32x4 acc[4];
        GATES1(acc, a0, bias0, Bh);
        unsigned hb;
        COMBINE1(acc, c0, hb);
        EXCH4(hb, h0w0, h0w1);
    }

    float xv1 = xrow[(T > 1) ? 1 : 0];               // x(t+1) for the loop

    // ---- steady state: iteration t does L1(t) || L0(t+1) (independent) ----
    for (int t = 0; t < T - 1; ++t) {
        const int tn = (t + 2 < T) ? (t + 2) : (T - 1);
        const float xn = xrow[tn];                   // prefetch x(t+2)

        const unsigned xw0 = pkh(fmaxf(fmaf(xv1, winq[0], binq[0]), 0.0f),
                                 fmaxf(fmaf(xv1, winq[1], binq[1]), 0.0f));
        const unsigned xw1 = pkh(fmaxf(fmaf(xv1, winq[2], binq[2]), 0.0f),
                                 fmaxf(fmaf(xv1, winq[3], binq[3]), 0.0f));

        const f16x8 B0h = frag4(xw0, xw1, h0w0, h0w1);   // [xi(t+1); h0(t)]
        const f16x8 B1h = frag4(h0w0, h0w1, h1w0, h1w1); // [h0(t); h1(t-1)]

        f32x4 acc0[4], acc1[4];
        GATES1(acc0, a0, bias0, B0h);                // L0(t+1)
        GATES1(acc1, a1, bias1, B1h);                // L1(t)

        unsigned hb0, hb1;
        COMBINE1(acc0, c0, hb0);                     // h0(t+1), this lane's unit
        COMBINE1(acc1, c1, hb1);                     // h1(t)

        EXCH4(hb0, h0w0, h0w1);
        EXCH4(hb1, h1w0, h1w1);
        xv1 = xn;
    }

    // ---- epilogue: L1(T-1) from h0(T-1), h1(T-2) ----
    {
        const f16x8 Bh = frag4(h0w0, h0w1, h1w0, h1w1);
        f32x4 acc[4];
        GATES1(acc, a1, bias1, Bh);
        unsigned hb;
        COMBINE1(acc, c1, hb);
        EXCH4(hb, h1w0, h1w1);
    }

    // ---- head: lanes with e<4 hold both words; write h1 rows ----
    if (!q0 && !q1) {
        htab[e][4 * g + 0] = unpk(h1w0, 0);
        htab[e][4 * g + 1] = unpk(h1w0, 1);
        htab[e][4 * g + 2] = unpk(h1w1, 0);
        htab[e][4 * g + 3] = unpk(h1w1, 1);
    }
    __syncthreads();
    if (lane < EPB) {
        const int ee = lane;
        float hv[16];
        #pragma unroll
        for (int k = 0; k < 16; ++k) hv[k] = htab[ee][k];
        float z[8];
        #pragma unroll
        for (int p = 0; p < 8; ++p) {
            float acc = fc_h_b[p];
            #pragma unroll
            for (int k = 0; k < 16; ++k) acc = fmaf(fc_h_w[p * 16 + k], hv[k], acc);
            z[p] = fmaxf(acc, 0.0f);
        }
        float o = fc_o_b[0];
        #pragma unroll
        for (int p = 0; p < 8; ++p) o = fmaf(fc_o_w[p], z[p], o);
        if (base + ee < B) out[base + ee] = o;
    }
}

extern "C" void kernel_launch(void* const* d_in, const int* in_sizes, int n_in,
                              void* d_out, int out_size, void* d_ws, size_t ws_size,
                              hipStream_t stream) {
    const float* x      = (const float*)d_in[0];
    const float* w_in   = (const float*)d_in[1];
    const float* b_in   = (const float*)d_in[2];
    const float* w_ih0  = (const float*)d_in[3];
    const float* w_hh0  = (const float*)d_in[4];
    const float* b_ih0  = (const float*)d_in[5];
    const float* b_hh0  = (const float*)d_in[6];
    const float* w_ih1  = (const float*)d_in[7];
    const float* w_hh1  = (const float*)d_in[8];
    const float* b_ih1  = (const float*)d_in[9];
    const float* b_hh1  = (const float*)d_in[10];
    const float* fc_h_w = (const float*)d_in[11];
    const float* fc_h_b = (const float*)d_in[12];
    const float* fc_o_w = (const float*)d_in[13];
    const float* fc_o_b = (const float*)d_in[14];

    const int B = out_size;                 // x is [B,T,1]
    const int T = in_sizes[0] / (B > 0 ? B : 1);
    const int grid = (B + EPB - 1) / EPB;   // 2048 blocks at B=8192

    hipLaunchKernelGGL(lstm_dup4, dim3(grid), dim3(64), 0, stream,
                       x, w_in, b_in, w_ih0, w_hh0, b_ih0, b_hh0,
                       w_ih1, w_hh1, b_ih1, b_hh1, fc_h_w, fc_h_b,
                       fc_o_w, fc_o_b, (float*)d_out, B, T);
}

// Round 26
// 122.715 us; speedup vs baseline: 1.3088x; 1.3088x over previous
//
#include <hip/hip_runtime.h>
#include <math.h>

// LSTMLightweight on MI355X (R26 = revert to R24, the verified best: 122.4us).
//   x[B,T,1] -> linear_in(1->16)+ReLU -> LSTM0(16) -> LSTM1(16) -> fc(16->8)+ReLU -> fc(8->1)
// Final ledger: R25 (4x dup, 2 waves/SIMD) regressed to 160us — per-element
// MFMA/pack issue doubled and outgrew the split-combine savings; the
// duplication lever's optimum is 2x (R24). All other anti-latency levers were
// falsified across R13-R25 (extra waves, >128-reg ILP, FMA-poly, LUT).
// R24 structure: 8 real elements/wave with B cols DUPLICATED (col e+8 = col e)
// -> lane pairs (g,e)/(g,e+8) hold identical acc; lane e<8 combines units
// q={0,1}, lane e>=8 q={2,3} -> 28 trans/step/lane; halves merged with ONE
// shfl_xor(8) per layer. 1024 one-wave blocks -> every SIMD active.
// Math: K-permuted A so B is lane-local (k=8g+i -> W_ih[.][4g+i] |
// W_hh[.][4g+i-4]; D row=4*(lane>>4)+q, col=lane&15), f16 single-product MFMA,
// one-rcp 7-trans cell, bias in C-init, L1(t) || L0(t+1) in-wave pipeline.

#define L2E 1.4426950408889634f
#define EPB 8         // REAL elements per wave/block (cols 8..15 duplicate 0..7)

typedef _Float16 f16x8 __attribute__((ext_vector_type(8)));
typedef float    f32x4 __attribute__((ext_vector_type(4)));
typedef int      i32x4 __attribute__((ext_vector_type(4)));

__device__ __forceinline__ unsigned pkh(float a, float b) {   // pack 2 f16 RTN
    const _Float16 ha = (_Float16)a, hb = (_Float16)b;
    return (unsigned)__builtin_bit_cast(unsigned short, ha) |
           ((unsigned)__builtin_bit_cast(unsigned short, hb) << 16);
}
__device__ __forceinline__ float unpk(unsigned w, int hi) {
    const unsigned short s = (unsigned short)(hi ? (w >> 16) : (w & 0xffffu));
    return (float)__builtin_bit_cast(_Float16, s);
}
__device__ __forceinline__ f16x8 frag4(unsigned w0, unsigned w1,
                                       unsigned w2, unsigned w3) {
    i32x4 t = {(int)w0, (int)w1, (int)w2, (int)w3};
    return __builtin_bit_cast(f16x8, t);
}

// one layer's gates, single product: acc[m] = bias[m] + A·B
#define GATES1(ACC, A, BIAS, BH)                                                      \
    _Pragma("unroll")                                                                 \
    for (int m = 0; m < 4; ++m) {                                                     \
        ACC[m] = BIAS[m];                                                             \
        ACC[m] = __builtin_amdgcn_mfma_f32_16x16x32_f16(A[m], BH, ACC[m], 0, 0, 0);   \
    }

// split combine: this lane handles 2 units (q0,q1) selected by hi8.
// one-rcp cell (7 trans/unit). Produces OWN = pkh(h_q0, h_q1); updates CA,CB.
#define COMBINE2(ACC, CA, CB, OWN)                                                    \
    do {                                                                              \
        const float aI0 = hi8 ? ACC[0][2] : ACC[0][0];                                \
        const float aI1 = hi8 ? ACC[0][3] : ACC[0][1];                                \
        const float aF0 = hi8 ? ACC[1][2] : ACC[1][0];                                \
        const float aF1 = hi8 ? ACC[1][3] : ACC[1][1];                                \
        const float aG0 = hi8 ? ACC[2][2] : ACC[2][0];                                \
        const float aG1 = hi8 ? ACC[2][3] : ACC[2][1];                                \
        const float aO0 = hi8 ? ACC[3][2] : ACC[3][0];                                \
        const float aO1 = hi8 ? ACC[3][3] : ACC[3][1];                                \
        /* unit 0 */                                                                  \
        const float Ei0 = __builtin_amdgcn_exp2f(-L2E * aI0);                         \
        const float Ef0 = __builtin_amdgcn_exp2f(-L2E * aF0);                         \
        const float Eg0 = __builtin_amdgcn_exp2f(fmaxf(aG0, -40.0f) * (-2.0f * L2E)); \
        const float Eo0 = __builtin_amdgcn_exp2f(-L2E * aO0);                         \
        const float fp0 = 1.0f + Ef0;                                                 \
        const float P0  = (1.0f + Ei0) * (1.0f + Eg0);                                \
        const float N0  = fmaf(CA, P0, (1.0f - Eg0) * fp0);                           \
        CA = N0 * __builtin_amdgcn_rcpf(fp0 * P0);                                    \
        const float Ec0 = __builtin_amdgcn_exp2f(fmaxf(CA, -40.0f) * (-2.0f * L2E));  \
        const float h0_ = (1.0f - Ec0) *                                              \
            __builtin_amdgcn_rcpf((1.0f + Eo0) * (1.0f + Ec0));                       \
        /* unit 1 */                                                                  \
        const float Ei1 = __builtin_amdgcn_exp2f(-L2E * aI1);                         \
        const float Ef1 = __builtin_amdgcn_exp2f(-L2E * aF1);                         \
        const float Eg1 = __builtin_amdgcn_exp2f(fmaxf(aG1, -40.0f) * (-2.0f * L2E)); \
        const float Eo1 = __builtin_amdgcn_exp2f(-L2E * aO1);                         \
        const float fp1 = 1.0f + Ef1;                                                 \
        const float P1  = (1.0f + Ei1) * (1.0f + Eg1);                                \
        const float N1  = fmaf(CB, P1, (1.0f - Eg1) * fp1);                           \
        CB = N1 * __builtin_amdgcn_rcpf(fp1 * P1);                                    \
        const float Ec1 = __builtin_amdgcn_exp2f(fmaxf(CB, -40.0f) * (-2.0f * L2E));  \
        const float h1_ = (1.0f - Ec1) *                                              \
            __builtin_amdgcn_rcpf((1.0f + Eo1) * (1.0f + Ec1));                       \
        OWN = pkh(h0_, h1_);                                                          \
    } while (0)

// exchange halves: lane pair (g,e)<->(g,e+8); w0 = units {4g,4g+1}, w1 = {4g+2,4g+3}
#define EXCH(OWN, W0, W1)                                                             \
    do {                                                                              \
        const unsigned oth_ = (unsigned)__shfl_xor((int)(OWN), 8, 64);                \
        W0 = hi8 ? oth_ : (OWN);                                                      \
        W1 = hi8 ? (OWN) : oth_;                                                      \
    } while (0)

__global__ __launch_bounds__(64) void lstm_dup(
    const float* __restrict__ x,
    const float* __restrict__ w_in, const float* __restrict__ b_in,
    const float* __restrict__ w_ih0, const float* __restrict__ w_hh0,
    const float* __restrict__ b_ih0, const float* __restrict__ b_hh0,
    const float* __restrict__ w_ih1, const float* __restrict__ w_hh1,
    const float* __restrict__ b_ih1, const float* __restrict__ b_hh1,
    const float* __restrict__ fc_h_w, const float* __restrict__ fc_h_b,
    const float* __restrict__ fc_o_w, const float* __restrict__ fc_o_b,
    float* __restrict__ out, int B, int T)
{
    const int lane = threadIdx.x;        // 0..63
    const int e    = lane & 15;          // B column (real elem = e&7)
    const int g    = lane >> 4;          // k-group / D-row group
    const bool hi8 = (e >= 8);
    const int base = blockIdx.x * EPB;
    int rowe = base + (e & 7); if (rowe >= B) rowe = B - 1;

    __shared__ float htab[EPB][16];      // head exchange only

    // ---- A-fragments (f16 RTN), K-permuted (A rows are gate rows — all real) ----
    f16x8 a0[4], a1[4];
    f32x4 bias0[4], bias1[4];
    #pragma unroll
    for (int m = 0; m < 4; ++m) {
        const int r = 16 * m + e;
        #pragma unroll
        for (int i = 0; i < 8; ++i) {
            const float w0 = (i < 4) ? w_ih0[r * 16 + 4 * g + i]
                                     : w_hh0[r * 16 + 4 * g + (i - 4)];
            const float w1 = (i < 4) ? w_ih1[r * 16 + 4 * g + i]
                                     : w_hh1[r * 16 + 4 * g + (i - 4)];
            a0[m][i] = (_Float16)w0;
            a1[m][i] = (_Float16)w1;
        }
        const int rd = 16 * m + 4 * g;
        #pragma unroll
        for (int q = 0; q < 4; ++q) {
            bias0[m][q] = b_ih0[rd + q] + b_hh0[rd + q];
            bias1[m][q] = b_ih1[rd + q] + b_hh1[rd + q];
        }
    }
    float winq[4], binq[4];
    #pragma unroll
    for (int q = 0; q < 4; ++q) { winq[q] = w_in[4 * g + q]; binq[q] = b_in[4 * g + q]; }

    // ---- state: this lane's 2 cells per layer; h as packed f16 words ----
    float c0A = 0.f, c0B = 0.f, c1A = 0.f, c1B = 0.f;
    unsigned h0w0, h0w1;                 // h0(t):  units {4g,4g+1}, {4g+2,4g+3}
    unsigned h1w0 = 0u, h1w1 = 0u;       // h1(t-1)

    const float* xrow = x + (size_t)rowe * T;

    // ---- prologue: L0 at t=0 (h0_{-1}=0) ----
    {
        const float xv = xrow[0];
        const unsigned xw0 = pkh(fmaxf(fmaf(xv, winq[0], binq[0]), 0.0f),
                                 fmaxf(fmaf(xv, winq[1], binq[1]), 0.0f));
        const unsigned xw1 = pkh(fmaxf(fmaf(xv, winq[2], binq[2]), 0.0f),
                                 fmaxf(fmaf(xv, winq[3], binq[3]), 0.0f));
        const f16x8 Bh = frag4(xw0, xw1, 0u, 0u);
        f32x4 acc[4];
        GATES1(acc, a0, bias0, Bh);
        unsigned own;
        COMBINE2(acc, c0A, c0B, own);
        EXCH(own, h0w0, h0w1);
    }

    float xv1 = xrow[(T > 1) ? 1 : 0];               // x(t+1) for the loop

    // ---- steady state: iteration t does L1(t) || L0(t+1) (independent) ----
    for (int t = 0; t < T - 1; ++t) {
        const int tn = (t + 2 < T) ? (t + 2) : (T - 1);
        const float xn = xrow[tn];                   // prefetch x(t+2)

        const unsigned xw0 = pkh(fmaxf(fmaf(xv1, winq[0], binq[0]), 0.0f),
                                 fmaxf(fmaf(xv1, winq[1], binq[1]), 0.0f));
        const unsigned xw1 = pkh(fmaxf(fmaf(xv1, winq[2], binq[2]), 0.0f),
                                 fmaxf(fmaf(xv1, winq[3], binq[3]), 0.0f));

        const f16x8 B0h = frag4(xw0, xw1, h0w0, h0w1);   // [xi(t+1); h0(t)]
        const f16x8 B1h = frag4(h0w0, h0w1, h1w0, h1w1); // [h0(t); h1(t-1)]

        f32x4 acc0[4], acc1[4];
        GATES1(acc0, a0, bias0, B0h);                // L0(t+1)
        GATES1(acc1, a1, bias1, B1h);                // L1(t)

        unsigned own0, own1;
        COMBINE2(acc0, c0A, c0B, own0);              // h0(t+1) halves
        COMBINE2(acc1, c1A, c1B, own1);              // h1(t) halves

        EXCH(own0, h0w0, h0w1);
        EXCH(own1, h1w0, h1w1);
        xv1 = xn;
    }

    // ---- epilogue: L1(T-1) from h0(T-1), h1(T-2) ----
    {
        const f16x8 Bh = frag4(h0w0, h0w1, h1w0, h1w1);
        f32x4 acc[4];
        GATES1(acc, a1, bias1, Bh);
        unsigned own;
        COMBINE2(acc, c1A, c1B, own);
        EXCH(own, h1w0, h1w1);
    }

    // ---- head: write final h1 (lanes e<8 hold both words after EXCH) ----
    if (!hi8) {
        htab[e][4 * g + 0] = unpk(h1w0, 0);
        htab[e][4 * g + 1] = unpk(h1w0, 1);
        htab[e][4 * g + 2] = unpk(h1w1, 0);
        htab[e][4 * g + 3] = unpk(h1w1, 1);
    }
    __syncthreads();
    if (lane < EPB) {
        const int ee = lane;
        float hv[16];
        #pragma unroll
        for (int k = 0; k < 16; ++k) hv[k] = htab[ee][k];
        float z[8];
        #pragma unroll
        for (int p = 0; p < 8; ++p) {
            float acc = fc_h_b[p];
            #pragma unroll
            for (int k = 0; k < 16; ++k) acc = fmaf(fc_h_w[p * 16 + k], hv[k], acc);
            z[p] = fmaxf(acc, 0.0f);
        }
        float o = fc_o_b[0];
        #pragma unroll
        for (int p = 0; p < 8; ++p) o = fmaf(fc_o_w[p], z[p], o);
        if (base + ee < B) out[base + ee] = o;
    }
}

extern "C" void kernel_launch(void* const* d_in, const int* in_sizes, int n_in,
                              void* d_out, int out_size, void* d_ws, size_t ws_size,
                              hipStream_t stream) {
    const float* x      = (const float*)d_in[0];
    const float* w_in   = (const float*)d_in[1];
    const float* b_in   = (const float*)d_in[2];
    const float* w_ih0  = (const float*)d_in[3];
    const float* w_hh0  = (const float*)d_in[4];
    const float* b_ih0  = (const float*)d_in[5];
    const float* b_hh0  = (const float*)d_in[6];
    const float* w_ih1  = (const float*)d_in[7];
    const float* w_hh1  = (const float*)d_in[8];
    const float* b_ih1  = (const float*)d_in[9];
    const float* b_hh1  = (const float*)d_in[10];
    const float* fc_h_w = (const float*)d_in[11];
    const float* fc_h_b = (const float*)d_in[12];
    const float* fc_o_w = (const float*)d_in[13];
    const float* fc_o_b = (const float*)d_in[14];

    const int B = out_size;                 // x is [B,T,1]
    const int T = in_sizes[0] / (B > 0 ? B : 1);
    const int grid = (B + EPB - 1) / EPB;   // 1024 blocks at B=8192

    hipLaunchKernelGGL(lstm_dup, dim3(grid), dim3(64), 0, stream,
                       x, w_in, b_in, w_ih0, w_hh0, b_ih0, b_hh0,
                       w_ih1, w_hh1, b_ih1, b_hh1, fc_h_w, fc_h_b,
                       fc_o_w, fc_o_b, (float*)d_out, B, T);
}